// Round 3
// baseline (193.380 us; speedup 1.0000x reference)
//
#include <hip/hip_runtime.h>

// PositionalEncoding: x[B,S,N,F] -> out[B,S,N,F+2], B=64,S=4096,N=25,F=3.
// out[...,0:3]=x; out[...,3]=||x_next-x||; out[...,4]=nan_to_num(acos(dot/(|x||x_next|)))
// x_next = step s+1 (self-pair at s=S-1).
//
// R2 post-mortem: kernel <76us (absent from rocprof top-5; 186us dur includes
// ~120us harness poison/restore). R2's 51.5 KB LDS capped occupancy at 3
// blocks/CU -> latency-bound. R3: single reused 20 KB LDS buffer, outputs
// staged in registers across one barrier -> 6-8 blocks/CU, same dense-float4
// global traffic (78.6 MB read + 131.1 MB write, ~33us floor at 6.3 TB/s).

constexpr int Nc = 25, Sc = 4096;
constexpr int BLOCK = 256;
constexpr int GPT = 4;                          // groups per thread
constexpr int GROUPS_PER_BLOCK = BLOCK * GPT;   // 1024
constexpr int IN_FLOATS  = GROUPS_PER_BLOCK * 3 + Nc * 3;  // 3147 (incl. +25-group overlap)
constexpr int IN_LOAD4   = (IN_FLOATS + 3) / 4;            // 787
constexpr int OUT_FLOATS = GROUPS_PER_BLOCK * 5;           // 5120 floats = 20 KB
constexpr long TOTAL_IN  = 64L * Sc * Nc * 3;              // 19,660,800 floats
constexpr int NUM_BLOCKS = (int)(64L * Sc * Nc / GROUPS_PER_BLOCK);  // 6400

__global__ __launch_bounds__(BLOCK) void pe_kernel(const float* __restrict__ x,
                                                   float* __restrict__ out) {
    __shared__ float s_buf[OUT_FLOATS];   // 20 KB, reused: input staging then output staging

    const int blk = blockIdx.x;
    const long base_in = (long)blk * (GROUPS_PER_BLOCK * 3);

    // ---- global -> LDS, dense float4 (787 float4; tail-clamped on last block) ----
    {
        const float4* __restrict__ src4 = (const float4*)(x + base_in);
        float4* d4 = (float4*)s_buf;
        #pragma unroll
        for (int k = 0; k < 4; ++k) {           // 4*256 >= 787
            int i = threadIdx.x + k * BLOCK;
            if (i < IN_LOAD4 && base_in + (long)(i + 1) * 4 <= TOTAL_IN)
                d4[i] = src4[i];
        }
    }
    __syncthreads();

    // ---- compute 4 groups/thread, outputs staged in registers ----
    float o[GPT * 5];
    {
        const int t = threadIdx.x;
        const int g0 = blk * GROUPS_PER_BLOCK + GPT * t;
        const int r0 = g0 / Nc;                 // magic-mul
        const int rem0 = g0 - r0 * Nc;
        const int lbase = 3 * GPT * t;          // local float idx of x for group j=0
        #pragma unroll
        for (int j = 0; j < GPT; ++j) {
            int rem = rem0 + j;
            int row = r0 + (rem >= Nc ? 1 : 0);
            bool self = ((row & (Sc - 1)) == Sc - 1);   // s == S-1 -> pair with itself
            int xo = lbase + 3 * j;
            int yo = self ? xo : xo + Nc * 3;

            float x0 = s_buf[xo],     x1 = s_buf[xo + 1], x2 = s_buf[xo + 2];
            float y0 = s_buf[yo],     y1 = s_buf[yo + 1], y2 = s_buf[yo + 2];

            float d0 = y0 - x0, d1 = y1 - x1, d2 = y2 - x2;
            float dist = sqrtf(d0 * d0 + d1 * d1 + d2 * d2);

            float dot = x0 * y0 + x1 * y1 + x2 * y2;
            float nx = sqrtf(x0 * x0 + x1 * x1 + x2 * x2);
            float ny = sqrtf(y0 * y0 + y1 * y1 + y2 * y2);
            float ang = acosf(dot / (nx * ny));  // NaN when |ratio|>1 from rounding
            if (isnan(ang)) ang = 0.0f;          // jnp.nan_to_num

            o[j * 5]     = x0;
            o[j * 5 + 1] = x1;
            o[j * 5 + 2] = x2;
            o[j * 5 + 3] = dist;
            o[j * 5 + 4] = ang;
        }
    }
    __syncthreads();   // all s_buf reads done before anyone overwrites it

    // ---- registers -> LDS (5 float4/thread at 80 B stride) ----
    {
        float4* w4 = (float4*)(s_buf + 20 * threadIdx.x);
        #pragma unroll
        for (int k = 0; k < 5; ++k)
            w4[k] = make_float4(o[k * 4], o[k * 4 + 1], o[k * 4 + 2], o[k * 4 + 3]);
    }
    __syncthreads();

    // ---- LDS -> global, dense unit-stride float4 (1280 float4) ----
    {
        const float4* s4 = (const float4*)s_buf;
        float4* __restrict__ dstg = (float4*)(out + (long)blk * OUT_FLOATS);
        #pragma unroll
        for (int k = 0; k < 5; ++k)
            dstg[threadIdx.x + k * BLOCK] = s4[threadIdx.x + k * BLOCK];
    }
}

extern "C" void kernel_launch(void* const* d_in, const int* in_sizes, int n_in,
                              void* d_out, int out_size, void* d_ws, size_t ws_size,
                              hipStream_t stream) {
    const float* x = (const float*)d_in[0];
    float* out = (float*)d_out;
    pe_kernel<<<NUM_BLOCKS, BLOCK, 0, stream>>>(x, out);
}